// Round 9
// baseline (148.049 us; speedup 1.0000x reference)
//
#include <hip/hip_runtime.h>
#include <hip/hip_bf16.h>
#include <math.h>

#define NCELLS 32000           // B*T
#define NP_ 6                  // mic pairs
#define IGN (-100)
#define CPB 8                  // cells per block
#define NBLK (NCELLS / CPB)    // 4000
#define THREADS 256            // 4 waves x 12 groups x 5 lanes (60/64 used)

// ---- lexicographic permutation table (matches itertools.permutations) ----
struct PermTable { int p[120][5]; };
constexpr PermTable make_perms() {
    PermTable t{};
    for (int i = 0; i < 120; ++i) {
        int avail[5] = {0, 1, 2, 3, 4};
        int rem = i;
        const int f[5] = {24, 6, 2, 1, 1};
        for (int k = 0; k < 5; ++k) {
            int d = rem / f[k];
            rem = rem % f[k];
            t.p[i][k] = avail[d];
            for (int m = d; m < 4 - k; ++m) avail[m] = avail[m + 1];
        }
    }
    return t;
}
__device__ constexpr PermTable PT = make_perms();

// ---------------------------------------------------------------------------
// Fused kernel. Phase 1 (threads 0..39): per-(cell,track) target scan with
// LDS rank-prefix -> classes into LDS scls[cell][pair][slot].
// Phase 2: 5 lanes per (cell,pair) (one per track). Each lane: 13 logit
// loads + lse/argmax for its track; 25 shfls build the full 5x5 loss matrix;
// every lane runs the static 120-perm scan (identical result, no exchange);
// lane tr contributes accuracy for position k=tr.
// ---------------------------------------------------------------------------
__global__ __launch_bounds__(THREADS) void tdoa_fused(
        const float* __restrict__ pred, const float* __restrict__ target,
        const float* __restrict__ mic,
        float* __restrict__ costp, int* __restrict__ vpp, int* __restrict__ crp) {
    __shared__ int cnt[CPB][5];
    __shared__ int scls[CPB][NP_][5];
    const int j = threadIdx.x;
    const int blk = blockIdx.x;

    // ---------------- phase 1: target scan (threads 0..CPB*5-1) -------------
    float fl[13];
    const int cellS = j / 5, trS = j - cellS * 5;
    const float* __restrict__ tg =
        target + (size_t)(blk * CPB + (cellS < CPB ? cellS : 0)) * 325 + trS * 65;
    if (j < CPB * 5) {
#pragma unroll
        for (int c = 0; c < 13; ++c) fl[c] = tg[c];   // active channel
        int mycnt = 0;
#pragma unroll
        for (int c = 0; c < 13; ++c) mycnt += (fl[c] != 0.0f) ? 1 : 0;
        cnt[cellS][trS] = mycnt;
    }
    __syncthreads();
    if (j < CPB * 5) {
        int base = 0, total = 0;
#pragma unroll
        for (int t = 0; t < 5; ++t) {
            int v = cnt[cellS][t];
            total += v;
            if (t < trS) base += v;
        }
        if (trS == 0) {   // fill unused slots with IGNORE (disjoint from writes)
            for (int s = (total < 5 ? total : 5); s < 5; ++s)
#pragma unroll
                for (int p = 0; p < 6; ++p) scls[cellS][p][s] = IGN;
        }
        float mx[4], my[4], mz[4];
#pragma unroll
        for (int m = 0; m < 4; ++m) {
            mx[m] = mic[m * 3 + 0];
            my[m] = mic[m * 3 + 1];
            mz[m] = mic[m * 3 + 2];
        }
        int slot = base;
#pragma unroll
        for (int c = 0; c < 13; ++c) {
            if (fl[c] != 0.0f) {
                if (slot < 5) {
                    float dist = tg[52 + c];              // channel 4
                    float sx = tg[13 + c] * dist;         // doa * dist
                    float sy = tg[26 + c] * dist;
                    float sz = tg[39 + c] * dist;
                    float d[4];
#pragma unroll
                    for (int m = 0; m < 4; ++m) {
                        float dx = sx - mx[m], dy = sy - my[m], dz = sz - mz[m];
                        d[m] = sqrtf(dx * dx + dy * dy + dz * dz);
                    }
                    const int Q0[6] = {0, 0, 0, 1, 1, 2};
                    const int Q1[6] = {1, 2, 3, 2, 3, 3};
#pragma unroll
                    for (int q = 0; q < 6; ++q) {
                        float td = (d[Q0[q]] - d[Q1[q]]) * (24000.0f / 343.0f);
                        int cls = (int)rintf(td) + 6;     // MAX_TAU = 6
                        cls = cls < 0 ? 0 : (cls > 12 ? 12 : cls);
                        scls[cellS][q][slot] = cls;
                    }
                }
                ++slot;
            }
        }
    }
    __syncthreads();

    // ---------------- phase 2: 5 lanes per (cell,pair) ----------------
    const int wave = j >> 6, lane = j & 63;
    float rc = 0.0f;
    int rv = 0, rr = 0;
    if (lane < 60) {
        const int grp = lane / 5, tr = lane - grp * 5;
        const int g = wave * 12 + grp;          // 0..47
        const int cellL = g / NP_, p = g - cellL * NP_;
        const float* __restrict__ L =
            pred + (size_t)(blk * CPB + cellL) * 390 + p;

        // my track's 13 logits -> max/argmax/lse
        float v[13];
#pragma unroll
        for (int c = 0; c < 13; ++c) v[c] = L[c * 30 + tr * 6];
        float m = v[0];
        int am = 0;
#pragma unroll
        for (int c = 1; c < 13; ++c) {
            if (v[c] > m) { m = v[c]; am = c; }   // strict > = first occurrence
        }
        float s = 0.0f;
#pragma unroll
        for (int c = 0; c < 13; ++c) s += __expf(v[c] - m);
        const float lse = m + __logf(s);

        // my loss-matrix column: lmc[slot] = -logp[tcs[slot]][tr]
        float lmc[5];
#pragma unroll
        for (int slot = 0; slot < 5; ++slot) {
            int tcs = scls[cellL][p][slot];
            bool val = (tcs != IGN);
            int tcc = val ? tcs : 0;
            float gl = L[tcc * 30 + tr * 6];      // L1 hit (sibling lines)
            lmc[slot] = val ? (lse - gl) : 0.0f;
        }

        // build full 5x5 via intra-group shfl (group base = grp*5 in-wave)
        const int gb5 = grp * 5;
        float lmf[5][5];
#pragma unroll
        for (int slot = 0; slot < 5; ++slot)
#pragma unroll
            for (int t = 0; t < 5; ++t)
                lmf[slot][t] = __shfl(lmc[slot], gb5 + t, 64);

        // static 120-perm scan — identical on all 5 lanes (no reduce needed)
        float best = 1e30f;
        int bi = 0;
#pragma unroll
        for (int i = 0; i < 120; ++i) {
            float c = lmf[0][PT.p[i][0]] + lmf[1][PT.p[i][1]]
                    + lmf[2][PT.p[i][2]] + lmf[3][PT.p[i][3]]
                    + lmf[4][PT.p[i][4]];
            if (c < best) { best = c; bi = i; }   // strict < = first min
        }
        if (tr == 0) rc = best * (1.0f / 5.0f);   // one cost per (cell,pair)

        // accuracy: lane tr handles position k = tr
        int slot = PT.p[bi][tr];                  // rodata gather (L1)
        int tc = scls[cellL][p][slot];            // dynamic LDS (allowed)
        if (tc != IGN) {
            rv = 1;
            rr = (am == tc) ? 1 : 0;
        }
    }

    // ---------------- block reduction ----------------
#pragma unroll
    for (int off = 32; off > 0; off >>= 1) {
        rc += __shfl_down(rc, off, 64);
        rv += __shfl_down(rv, off, 64);
        rr += __shfl_down(rr, off, 64);
    }
    __shared__ float sf[4];
    __shared__ int sv[4], sc2[4];
    if (lane == 0) { sf[wave] = rc; sv[wave] = rv; sc2[wave] = rr; }
    __syncthreads();
    if (j == 0) {
        costp[blk] = sf[0] + sf[1] + sf[2] + sf[3];
        vpp[blk]   = sv[0] + sv[1] + sv[2] + sv[3];
        crp[blk]   = sc2[0] + sc2[1] + sc2[2] + sc2[3];
    }
}

__global__ __launch_bounds__(256) void tdoa_final(
        const float* __restrict__ costp, const int* __restrict__ vpp,
        const int* __restrict__ crp, float* __restrict__ out) {
    __shared__ float sf[4];
    __shared__ int sv[4], sc[4];
    int j = threadIdx.x;
    float c = 0.0f;
    int v = 0, r = 0;
    for (int i = j; i < NBLK; i += 256) {
        c += costp[i];
        v += vpp[i];
        r += crp[i];
    }
#pragma unroll
    for (int off = 32; off > 0; off >>= 1) {
        c += __shfl_down(c, off, 64);
        v += __shfl_down(v, off, 64);
        r += __shfl_down(r, off, 64);
    }
    int wave = j >> 6, lane = j & 63;
    if (lane == 0) { sf[wave] = c; sv[wave] = v; sc[wave] = r; }
    __syncthreads();
    if (j == 0) {
        float tc = sf[0] + sf[1] + sf[2] + sf[3];
        int tv = sv[0] + sv[1] + sv[2] + sv[3];
        int trr = sc[0] + sc[1] + sc[2] + sc[3];
        out[0] = tc / (float)(NCELLS * NP_);                   // loss
        out[1] = (tv > 0) ? ((float)trr / (float)tv) : 0.0f;   // acc
    }
}

extern "C" void kernel_launch(void* const* d_in, const int* in_sizes, int n_in,
                              void* d_out, int out_size, void* d_ws, size_t ws_size,
                              hipStream_t stream) {
    const float* pred   = (const float*)d_in[0];
    const float* target = (const float*)d_in[1];
    const float* mic    = (const float*)d_in[2];
    float* out = (float*)d_out;

    float* costp = (float*)d_ws;
    int*   vpp   = (int*)((char*)d_ws + NBLK * 4);
    int*   crp   = (int*)((char*)d_ws + NBLK * 8);

    tdoa_fused<<<NBLK, THREADS, 0, stream>>>(pred, target, mic, costp, vpp, crp);
    tdoa_final<<<1, 256, 0, stream>>>(costp, vpp, crp, out);
}

// Round 14
// 136.618 us; speedup vs baseline: 1.0837x; 1.0837x over previous
//
#include <hip/hip_runtime.h>
#include <hip/hip_bf16.h>
#include <math.h>

#define NCELLS 32000           // B*T
#define NP_ 6                  // mic pairs
#define IGN (-100)
#define CPB 8                  // cells per block
#define NBLK (NCELLS / CPB)    // 4000
#define THREADS 256            // 4 waves x 12 groups x 5 lanes (60/64 used)

// ---- lexicographic permutation table (matches itertools.permutations) ----
struct PermTable { int p[120][5]; };
constexpr PermTable make_perms() {
    PermTable t{};
    for (int i = 0; i < 120; ++i) {
        int avail[5] = {0, 1, 2, 3, 4};
        int rem = i;
        const int f[5] = {24, 6, 2, 1, 1};
        for (int k = 0; k < 5; ++k) {
            int d = rem / f[k];
            rem = rem % f[k];
            t.p[i][k] = avail[d];
            for (int m = d; m < 4 - k; ++m) avail[m] = avail[m + 1];
        }
    }
    return t;
}
__device__ constexpr PermTable PT = make_perms();

// ---- static 24 perms of {0,1,2,3}, lexicographic (inner-chunk pattern) ----
struct Perm4 { int p[24][4]; };
constexpr Perm4 make_p4() {
    Perm4 t{};
    for (int i = 0; i < 24; ++i) {
        int avail[4] = {0, 1, 2, 3};
        int rem = i;
        const int f[4] = {6, 2, 1, 1};
        for (int k = 0; k < 4; ++k) {
            int d = rem / f[k];
            rem = rem % f[k];
            t.p[i][k] = avail[d];
            for (int m = d; m < 3 - k; ++m) avail[m] = avail[m + 1];
        }
    }
    return t;
}
__device__ constexpr Perm4 P4 = make_p4();

// ---------------------------------------------------------------------------
// Fused kernel. Phase 1 (threads 0..CPB*5-1): per-(cell,track) target scan
// with LDS rank-prefix -> classes into LDS scls[cell][pair][slot].
// Phase 2: 5 lanes per (cell,pair), one per track. Each lane: 13 logit loads
// + lse/argmax for its track; 20 shfls build lm[slot][track] for slots 1..4;
// each lane scans the 24 perms whose FIRST element is its track (static P4
// pattern + runtime avail select keeps all register indices static); 5-lane
// argmin combine in chunk order preserves first-min tie-break.
// ---------------------------------------------------------------------------
__global__ __launch_bounds__(THREADS) void tdoa_fused(
        const float* __restrict__ pred, const float* __restrict__ target,
        const float* __restrict__ mic,
        float* __restrict__ costp, int* __restrict__ vpp, int* __restrict__ crp) {
    __shared__ int cnt[CPB][5];
    __shared__ int scls[CPB][NP_][5];
    const int j = threadIdx.x;
    const int blk = blockIdx.x;

    // ---------------- phase 1: target scan (threads 0..CPB*5-1) -------------
    float fl[13];
    const int cellS = j / 5, trS = j - cellS * 5;
    const float* __restrict__ tg =
        target + (size_t)(blk * CPB + (cellS < CPB ? cellS : 0)) * 325 + trS * 65;
    if (j < CPB * 5) {
#pragma unroll
        for (int c = 0; c < 13; ++c) fl[c] = tg[c];   // active channel
        int mycnt = 0;
#pragma unroll
        for (int c = 0; c < 13; ++c) mycnt += (fl[c] != 0.0f) ? 1 : 0;
        cnt[cellS][trS] = mycnt;
    }
    __syncthreads();
    if (j < CPB * 5) {
        int base = 0, total = 0;
#pragma unroll
        for (int t = 0; t < 5; ++t) {
            int v = cnt[cellS][t];
            total += v;
            if (t < trS) base += v;
        }
        if (trS == 0) {   // fill unused slots with IGNORE (disjoint writes)
            for (int s = (total < 5 ? total : 5); s < 5; ++s)
#pragma unroll
                for (int p = 0; p < 6; ++p) scls[cellS][p][s] = IGN;
        }
        float mx[4], my[4], mz[4];
#pragma unroll
        for (int m = 0; m < 4; ++m) {
            mx[m] = mic[m * 3 + 0];
            my[m] = mic[m * 3 + 1];
            mz[m] = mic[m * 3 + 2];
        }
        int slot = base;
#pragma unroll
        for (int c = 0; c < 13; ++c) {
            if (fl[c] != 0.0f) {
                if (slot < 5) {
                    float dist = tg[52 + c];              // channel 4
                    float sx = tg[13 + c] * dist;         // doa * dist
                    float sy = tg[26 + c] * dist;
                    float sz = tg[39 + c] * dist;
                    float d[4];
#pragma unroll
                    for (int m = 0; m < 4; ++m) {
                        float dx = sx - mx[m], dy = sy - my[m], dz = sz - mz[m];
                        d[m] = sqrtf(dx * dx + dy * dy + dz * dz);
                    }
                    const int Q0[6] = {0, 0, 0, 1, 1, 2};
                    const int Q1[6] = {1, 2, 3, 2, 3, 3};
#pragma unroll
                    for (int q = 0; q < 6; ++q) {
                        float td = (d[Q0[q]] - d[Q1[q]]) * (24000.0f / 343.0f);
                        int cls = (int)rintf(td) + 6;     // MAX_TAU = 6
                        cls = cls < 0 ? 0 : (cls > 12 ? 12 : cls);
                        scls[cellS][q][slot] = cls;
                    }
                }
                ++slot;
            }
        }
    }
    __syncthreads();

    // ---------------- phase 2: 5 lanes per (cell,pair) ----------------
    const int wave = j >> 6, lane = j & 63;
    float rc = 0.0f;
    int rv = 0, rr = 0;
    if (lane < 60) {
        const int grp = lane / 5, tr = lane - grp * 5;
        const int g = wave * 12 + grp;          // 0..47
        const int cellL = g / NP_, p = g - cellL * NP_;
        const float* __restrict__ L =
            pred + (size_t)(blk * CPB + cellL) * 390 + p;

        // my track's 13 logits -> max/argmax/lse
        float v[13];
#pragma unroll
        for (int c = 0; c < 13; ++c) v[c] = L[c * 30 + tr * 6];
        float m = v[0];
        int am = 0;
#pragma unroll
        for (int c = 1; c < 13; ++c) {
            if (v[c] > m) { m = v[c]; am = c; }   // strict > = first occurrence
        }
        float s = 0.0f;
#pragma unroll
        for (int c = 0; c < 13; ++c) s += __expf(v[c] - m);
        const float lse = m + __logf(s);

        // my loss-matrix column: lmc[slot] = lm[slot][tr]
        float lmc[5];
#pragma unroll
        for (int slot = 0; slot < 5; ++slot) {
            int tcs = scls[cellL][p][slot];
            bool val = (tcs != IGN);
            int tcc = val ? tcs : 0;
            float gl = L[tcc * 30 + tr * 6];      // L1 hit (sibling lines)
            lmc[slot] = val ? (lse - gl) : 0.0f;
        }

        // all-gather lm[slot][t] for slots 1..4 (20 shfls within 5-lane group)
        const int gb5 = grp * 5;
        float lmf_[4][5];
#pragma unroll
        for (int sl = 1; sl <= 4; ++sl)
#pragma unroll
            for (int t = 0; t < 5; ++t)
                lmf_[sl - 1][t] = __shfl(lmc[sl], gb5 + t, 64);

        // lm2[s][m] = lm[s+1][avail[m]], avail = {0..4}\{tr}  (static indices)
        float lm2[4][4];
#pragma unroll
        for (int s2 = 0; s2 < 4; ++s2)
#pragma unroll
            for (int mm = 0; mm < 4; ++mm)
                lm2[s2][mm] = (mm < tr) ? lmf_[s2][mm] : lmf_[s2][mm + 1];

        // scan my 24-perm chunk (global rows tr*24 .. tr*24+23), static P4
        const float base0 = lmc[0];               // lm[0][tr]
        float best = 1e30f;
        int bi = 0;
#pragma unroll
        for (int i = 0; i < 24; ++i) {
            float c = base0 + lm2[0][P4.p[i][0]] + lm2[1][P4.p[i][1]]
                    + lm2[2][P4.p[i][2]] + lm2[3][P4.p[i][3]];
            if (c < best) { best = c; bi = i; }   // strict < = first in chunk
        }
        int gl_i = tr * 24 + bi;

        // combine across 5 lanes in chunk (=index) order -> global first-min
        float gbest = 1e30f;
        int gbi = 0;
#pragma unroll
        for (int t = 0; t < 5; ++t) {
            float cb = __shfl(best, gb5 + t, 64);
            int ib = __shfl(gl_i, gb5 + t, 64);
            if (cb < gbest) { gbest = cb; gbi = ib; }
        }
        if (tr == 0) rc = gbest * (1.0f / 5.0f);  // one cost per (cell,pair)

        // accuracy: lane tr handles position k = tr
        int slot = PT.p[gbi][tr];                 // rodata gather (L1)
        int tc = scls[cellL][p][slot];            // dynamic LDS (allowed)
        if (tc != IGN) {
            rv = 1;
            rr = (am == tc) ? 1 : 0;
        }
    }

    // ---------------- block reduction ----------------
#pragma unroll
    for (int off = 32; off > 0; off >>= 1) {
        rc += __shfl_down(rc, off, 64);
        rv += __shfl_down(rv, off, 64);
        rr += __shfl_down(rr, off, 64);
    }
    __shared__ float sf[4];
    __shared__ int sv[4], sc2[4];
    if (lane == 0) { sf[wave] = rc; sv[wave] = rv; sc2[wave] = rr; }
    __syncthreads();
    if (j == 0) {
        costp[blk] = sf[0] + sf[1] + sf[2] + sf[3];
        vpp[blk]   = sv[0] + sv[1] + sv[2] + sv[3];
        crp[blk]   = sc2[0] + sc2[1] + sc2[2] + sc2[3];
    }
}

__global__ __launch_bounds__(256) void tdoa_final(
        const float* __restrict__ costp, const int* __restrict__ vpp,
        const int* __restrict__ crp, float* __restrict__ out) {
    __shared__ float sf[4];
    __shared__ int sv[4], sc[4];
    int j = threadIdx.x;
    float c = 0.0f;
    int v = 0, r = 0;
    for (int i = j; i < NBLK; i += 256) {
        c += costp[i];
        v += vpp[i];
        r += crp[i];
    }
#pragma unroll
    for (int off = 32; off > 0; off >>= 1) {
        c += __shfl_down(c, off, 64);
        v += __shfl_down(v, off, 64);
        r += __shfl_down(r, off, 64);
    }
    int wave = j >> 6, lane = j & 63;
    if (lane == 0) { sf[wave] = c; sv[wave] = v; sc[wave] = r; }
    __syncthreads();
    if (j == 0) {
        float tc = sf[0] + sf[1] + sf[2] + sf[3];
        int tv = sv[0] + sv[1] + sv[2] + sv[3];
        int trr = sc[0] + sc[1] + sc[2] + sc[3];
        out[0] = tc / (float)(NCELLS * NP_);                   // loss
        out[1] = (tv > 0) ? ((float)trr / (float)tv) : 0.0f;   // acc
    }
}

extern "C" void kernel_launch(void* const* d_in, const int* in_sizes, int n_in,
                              void* d_out, int out_size, void* d_ws, size_t ws_size,
                              hipStream_t stream) {
    const float* pred   = (const float*)d_in[0];
    const float* target = (const float*)d_in[1];
    const float* mic    = (const float*)d_in[2];
    float* out = (float*)d_out;

    float* costp = (float*)d_ws;
    int*   vpp   = (int*)((char*)d_ws + NBLK * 4);
    int*   crp   = (int*)((char*)d_ws + NBLK * 8);

    tdoa_fused<<<NBLK, THREADS, 0, stream>>>(pred, target, mic, costp, vpp, crp);
    tdoa_final<<<1, 256, 0, stream>>>(costp, vpp, crp, out);
}